// Round 7
// baseline (314.025 us; speedup 1.0000x reference)
//
#include <hip/hip_runtime.h>
#include <math.h>

#define NTOT   32000      // total nodes
#define NNODE  2000       // nodes per graph
#define NB     16         // batch (graphs)
#define FIN    128        // input features
#define HCDIM  256        // heads*channels
#define NH     4          // heads
#define FC1DIM 512
#define FC2DIM 128
#define FCIN   12000      // 6*NNODE
#define KC1    50         // fc1 k-rows per block
#define NCH1   240        // 12000/KC1
#define CAP    64         // padded adjacency capacity per node (deg ~ Poisson(12))
#define BK     32
#define LPITCH 40         // LDS row pitch in bf16 (80B: 16B-aligned, bank-spread)
#define TRB    384        // (HCDIM*FIN + HCDIM*HCDIM)/256 transpose blocks
#define DEMOB  375        // NB*3*NNODE/256 demo blocks
#define T1B    32         // NB*FC1DIM/256 t1-zero blocks

typedef __attribute__((ext_vector_type(8))) short bf16x8;
typedef __attribute__((ext_vector_type(4))) float f32x4;

// ---------- small helpers ----------
__device__ inline float4 ld4(const float* p){ return *reinterpret_cast<const float4*>(p); }
__device__ inline void st4(float* p, float4 v){ *reinterpret_cast<float4*>(p) = v; }
__device__ inline float4 add4(float4 a, float4 b){ return make_float4(a.x+b.x,a.y+b.y,a.z+b.z,a.w+b.w); }
__device__ inline float lrelu(float x){ return x > 0.f ? x : 0.2f*x; }
__device__ inline float4 leaky4(float4 a){ return make_float4(lrelu(a.x),lrelu(a.y),lrelu(a.z),lrelu(a.w)); }
__device__ inline float4 exp4u(float4 a){ return make_float4(__expf(a.x),__expf(a.y),__expf(a.z),__expf(a.w)); }
__device__ inline float dot4(float4 a, float4 b){ return a.x*b.x + a.y*b.y + a.z*b.z + a.w*b.w; }
__device__ inline float selh(float4 v, int h){ return h==0 ? v.x : (h==1 ? v.y : (h==2 ? v.z : v.w)); }

__device__ inline unsigned short f2bf(float f){
  unsigned int u = __float_as_uint(f);
  u += 0x7FFFu + ((u >> 16) & 1u);
  return (unsigned short)(u >> 16);
}
__device__ inline float bf2f(unsigned short h){
  return __uint_as_float(((unsigned int)h) << 16);
}
__device__ inline float4 ldbf4(const unsigned short* p){
  ushort4 v = *reinterpret_cast<const ushort4*>(p);
  return make_float4(bf2f(v.x), bf2f(v.y), bf2f(v.z), bf2f(v.w));
}

// ---------- fused: x0 = mean(x,-1), xb = bf16(x), cnt = 0; one wave per row ----------
__global__ __launch_bounds__(256) void k_prep(const float* __restrict__ x,
                                              unsigned short* __restrict__ xb,
                                              float* __restrict__ x0r,
                                              int* __restrict__ cnt){
  int gid = blockIdx.x*256 + threadIdx.x;
  if(gid < NTOT) cnt[gid] = 0;
  int lane = threadIdx.x & 63, wv = threadIdx.x >> 6;
  int n = blockIdx.x*4 + wv;
  const float* r = x + (size_t)n*FIN;
  float2 v = *reinterpret_cast<const float2*>(r + lane*2);
  unsigned int packed = (unsigned int)f2bf(v.x) | ((unsigned int)f2bf(v.y) << 16);
  *reinterpret_cast<unsigned int*>(xb + (size_t)n*FIN + lane*2) = packed;
  float s = v.x + v.y;
  #pragma unroll
  for(int off=1; off<64; off<<=1) s += __shfl_xor(s, off);
  if(lane == 0) x0r[n] = s * (1.0f/FIN);
}

// ---------- misc: adjacency build | W transposes | demo fill | t1 zero ----------
__global__ void k_misc(const int* __restrict__ src, const int* __restrict__ dst,
                       int* __restrict__ cnt, int* __restrict__ col, int e0, int eb,
                       const float* __restrict__ W1, const float* __restrict__ W2,
                       unsigned short* __restrict__ W1t, unsigned short* __restrict__ W2t,
                       const float* __restrict__ sexemb, const float* __restrict__ mutemb,
                       const float* __restrict__ agew, const float* __restrict__ ageb,
                       const float* __restrict__ age, const int* __restrict__ sex,
                       const int* __restrict__ mut, float* __restrict__ t,
                       float* __restrict__ t1){
  int blk = blockIdx.x;
  if(blk < eb){                                   // ---- adjacency build
    int i = blk*256 + threadIdx.x;
    if(i < e0){
      int d = dst[i];
      int slot = atomicAdd(&cnt[d], 1);
      if(slot < CAP) col[(d<<6) + slot] = src[i];
    }
  } else if(blk < eb + TRB){                      // ---- weight transposes + bf16
    int idx = (blk - eb)*256 + threadIdx.x;
    if(idx < HCDIM*FIN){
      int n = idx / FIN, k = idx - n*FIN;
      W1t[idx] = f2bf(W1[(size_t)k*HCDIM + n]);
    } else {
      int j = idx - HCDIM*FIN;
      int n = j / HCDIM, k = j - n*HCDIM;
      W2t[j] = f2bf(W2[(size_t)k*HCDIM + n]);
    }
  } else if(blk < eb + TRB + DEMOB){              // ---- demographic part of t
    int i = (blk - eb - TRB)*256 + threadIdx.x;
    int b = i / (3*NNODE);
    int j = i - b*(3*NNODE);
    float v;
    if(j < NNODE)          v = sexemb[sex[b]*NNODE + j];
    else if(j < 2*NNODE)   v = mutemb[mut[b]*NNODE + (j - NNODE)];
    else                   v = age[b]*agew[j - 2*NNODE] + ageb[j - 2*NNODE];
    t[b*FCIN + j] = v;
  } else {                                        // ---- zero t1 (atomic fc1 target)
    int i = (blk - eb - TRB - DEMOB)*256 + threadIdx.x;
    t1[i] = 0.f;
  }
}

// ---------- bf16 MFMA GEMM + fused attention coefficients ----------
// C[M,256] = A[M,K] @ Bt[256,K]^T. 128x128 tile, 4 waves, 64x64 quadrant each.
// Each wave's 64 columns == exactly one head's channels -> compute a_s/a_d from f32 acc.
__global__ __launch_bounds__(256) void k_gemm_bf(const unsigned short* __restrict__ A,
                                                 const unsigned short* __restrict__ Bt,
                                                 unsigned short* __restrict__ C,
                                                 const float* __restrict__ attS,
                                                 const float* __restrict__ attD,
                                                 float* __restrict__ a_s,
                                                 float* __restrict__ a_d,
                                                 int M, int K){
  __shared__ unsigned short As[128][LPITCH];
  __shared__ unsigned short Bs[128][LPITCH];
  int tid = threadIdx.x;
  int lane = tid & 63, wv = tid >> 6;
  int wm = (wv & 1)*64, wn = (wv >> 1)*64;
  int m0 = blockIdx.y*128, n0 = blockIdx.x*128;
  int l15 = lane & 15, lq = lane >> 4;
  f32x4 acc[4][4];
  #pragma unroll
  for(int i=0;i<4;i++)
    #pragma unroll
    for(int j=0;j<4;j++)
      acc[i][j] = (f32x4){0.f,0.f,0.f,0.f};

  int r = tid >> 2, c = (tid & 3)*8;
  for(int k0 = 0; k0 < K; k0 += BK){
    *reinterpret_cast<uint4*>(&As[r][c])    = *reinterpret_cast<const uint4*>(A  + (size_t)(m0+r)*K + k0 + c);
    *reinterpret_cast<uint4*>(&As[r+64][c]) = *reinterpret_cast<const uint4*>(A  + (size_t)(m0+r+64)*K + k0 + c);
    *reinterpret_cast<uint4*>(&Bs[r][c])    = *reinterpret_cast<const uint4*>(Bt + (size_t)(n0+r)*K + k0 + c);
    *reinterpret_cast<uint4*>(&Bs[r+64][c]) = *reinterpret_cast<const uint4*>(Bt + (size_t)(n0+r+64)*K + k0 + c);
    __syncthreads();
    bf16x8 af[4], bfr[4];
    #pragma unroll
    for(int i=0;i<4;i++){
      af[i]  = *reinterpret_cast<const bf16x8*>(&As[wm + i*16 + l15][lq*8]);
      bfr[i] = *reinterpret_cast<const bf16x8*>(&Bs[wn + i*16 + l15][lq*8]);
    }
    #pragma unroll
    for(int mi=0;mi<4;mi++)
      #pragma unroll
      for(int ni=0;ni<4;ni++)
        acc[mi][ni] = __builtin_amdgcn_mfma_f32_16x16x32_bf16(af[mi], bfr[ni], acc[mi][ni], 0, 0, 0);
    __syncthreads();
  }
  // C/D layout: col = lane&15, row = (lane>>4)*4 + reg
  #pragma unroll
  for(int mi=0;mi<4;mi++){
    #pragma unroll
    for(int ni=0;ni<4;ni++){
      int cn = n0 + wn + ni*16 + l15;
      #pragma unroll
      for(int rg=0;rg<4;rg++){
        int rm = m0 + wm + mi*16 + lq*4 + rg;
        C[(size_t)rm*HCDIM + cn] = f2bf(acc[mi][ni][rg]);
      }
    }
  }
  // fused attention coefficients: this wave's 64 cols = head (n0+wn)/64
  int head = (n0 + wn) >> 6;
  float avs[4], avd[4];
  #pragma unroll
  for(int ni=0;ni<4;ni++){
    int cc = ni*16 + l15;
    avs[ni] = attS[head*64 + cc];
    avd[ni] = attD[head*64 + cc];
  }
  #pragma unroll
  for(int mi=0;mi<4;mi++){
    #pragma unroll
    for(int rg=0;rg<4;rg++){
      float ps = 0.f, pd = 0.f;
      #pragma unroll
      for(int ni=0;ni<4;ni++){
        float v = acc[mi][ni][rg];
        ps = fmaf(avs[ni], v, ps);
        pd = fmaf(avd[ni], v, pd);
      }
      #pragma unroll
      for(int off=1; off<16; off<<=1){
        ps += __shfl_xor(ps, off);
        pd += __shfl_xor(pd, off);
      }
      if(l15 == 0){
        int rm = m0 + wm + mi*16 + lq*4 + rg;
        a_s[rm*4 + head] = ps;
        a_d[rm*4 + head] = pd;
      }
    }
  }
}

// ---------- fused softmax + aggregation + bias + relu + pool-dot ----------
// No max-subtraction (|alpha| <~ 1.5 -> exp safe); denominator accumulated per lane
// in the serial loop; col + edge-weights cached in per-wave LDS; no block barrier.
template<int STORE>
__global__ __launch_bounds__(256) void k_agg(const unsigned short* __restrict__ hpre,
                                             const float* __restrict__ a_s,
                                             const float* __restrict__ a_d,
                                             const int* __restrict__ cnt,
                                             const int* __restrict__ col,
                                             const float* __restrict__ bias,
                                             const float* __restrict__ pw,
                                             const float* __restrict__ pb,
                                             unsigned short* __restrict__ hout,
                                             float* __restrict__ xraw){
  __shared__ float4 ew[4][CAP];
  __shared__ int    cols[4][CAP];
  int tid = threadIdx.x;
  int lane = tid & 63, wv = tid >> 6;
  // swizzle: graph g on XCD g%8 so its ~1MB of bf16 hpre rows stays L2-resident
  int blk  = blockIdx.x;
  int xcd  = blk & 7;
  int slot = blk >> 3;
  int half = slot / 500;
  int g    = xcd + 8*half;
  int n    = g*NNODE + (slot - half*500)*4 + wv;
  int f0 = lane*4;
  int hl = lane >> 4;
  float4 ad   = ld4(a_d + n*4);
  float4 asn  = ld4(a_s + n*4);
  float4 eself = exp4u(leaky4(add4(asn, ad)));   // unnormalized self weight
  int deg = min(cnt[n], CAP);
  int base = n << 6;
  if(lane < deg){
    int s = col[base + lane];
    cols[wv][lane] = s;
    ew[wv][lane] = exp4u(leaky4(add4(ld4(a_s + s*4), ad)));
  }
  float es = selh(eself, hl);
  float dsum = es;
  float4 hv = ldbf4(hpre + (size_t)n*HCDIM + f0);
  float4 acc = make_float4(es*hv.x, es*hv.y, es*hv.z, es*hv.w);
  const float* ewf = (const float*)&ew[wv][0];
  const int*   cwf = &cols[wv][0];
  for(int e = 0; e < deg; e++){
    int s = cwf[e];                       // LDS broadcast (wave-uniform)
    float w = ewf[e*4 + hl];
    dsum += w;
    float4 h2 = ldbf4(hpre + (size_t)s*HCDIM + f0);
    acc.x = fmaf(w, h2.x, acc.x); acc.y = fmaf(w, h2.y, acc.y);
    acc.z = fmaf(w, h2.z, acc.z); acc.w = fmaf(w, h2.w, acc.w);
  }
  float invh = 1.0f / (dsum + 1e-16f);
  float4 b4 = ld4(bias + f0);
  acc = make_float4(fmaxf(fmaf(acc.x,invh,b4.x),0.f), fmaxf(fmaf(acc.y,invh,b4.y),0.f),
                    fmaxf(fmaf(acc.z,invh,b4.z),0.f), fmaxf(fmaf(acc.w,invh,b4.w),0.f));
  if(STORE){
    ushort4 hb = make_ushort4(f2bf(acc.x), f2bf(acc.y), f2bf(acc.z), f2bf(acc.w));
    *reinterpret_cast<ushort4*>(hout + (size_t)n*HCDIM + f0) = hb;
  }
  float part = dot4(acc, ld4(pw + f0));
  #pragma unroll
  for(int off=1; off<64; off<<=1) part += __shfl_xor(part, off);
  if(lane == 0) xraw[n] = part + pb[0];
}

// ---------- all three layernorms in one launch: blk = which*16 + b ----------
__global__ __launch_bounds__(256) void k_ln3(const float* __restrict__ xraw0,
                                             const float* __restrict__ lnw,
                                             const float* __restrict__ lnb,
                                             float* __restrict__ out,
                                             float* __restrict__ t){
  int blk = blockIdx.x;
  int b = blk & 15, which = blk >> 4;
  const float* src = xraw0 + which*NTOT + b*NNODE;
  __shared__ float red[8];
  int tid = threadIdx.x, lane = tid & 63, wv = tid >> 6;
  float s = 0.f, ss = 0.f;
  for(int i = tid; i < NNODE; i += 256){ float v = src[i]; s += v; ss += v*v; }
  #pragma unroll
  for(int off=1; off<64; off<<=1){ s += __shfl_xor(s, off); ss += __shfl_xor(ss, off); }
  if(lane == 0){ red[wv] = s; red[4+wv] = ss; }
  __syncthreads();
  s  = red[0]+red[1]+red[2]+red[3];
  ss = red[4]+red[5]+red[6]+red[7];
  float mu  = s * (1.0f/NNODE);
  float var = ss * (1.0f/NNODE) - mu*mu;
  float inv = 1.0f / sqrtf(var + 1e-5f);
  float* o1 = out + 16 + which*(NB*NNODE) + b*NNODE;
  float* o2 = out + 16 + 3*(NB*NNODE) + b*(3*NNODE) + which*NNODE;
  float* o3 = t + b*FCIN + 3*NNODE + which*NNODE;
  for(int i = tid; i < NNODE; i += 256){
    float v = (src[i]-mu)*inv*lnw[i] + lnb[i];
    o1[i] = v; o2[i] = v; o3[i] = v;
  }
}

// ---------- FC1: 240-way split-K, atomic accumulate into t1 ----------
__global__ __launch_bounds__(256) void k_fc1p(const float* __restrict__ t,
                                              const float* __restrict__ fw1,
                                              float* __restrict__ t1){
  __shared__ float ts[NB][KC1];
  __shared__ float red[NB][FC1DIM];
  int tid = threadIdx.x;
  int half = tid >> 7;
  int c4 = (tid & 127) * 4;
  int k0 = blockIdx.x * KC1;
  for(int i = tid; i < NB*KC1; i += 256){
    int b = i / KC1, kk = i - b*KC1;
    ts[b][kk] = t[b*FCIN + k0 + kk];
  }
  __syncthreads();
  float4 acc[NB];
  #pragma unroll
  for(int b=0;b<NB;b++) acc[b] = make_float4(0.f,0.f,0.f,0.f);
  for(int kk = half; kk < KC1; kk += 2){
    float4 w = ld4(fw1 + (size_t)(k0+kk)*FC1DIM + c4);
    #pragma unroll
    for(int b=0;b<NB;b++){
      float tv = ts[b][kk];
      acc[b].x = fmaf(tv, w.x, acc[b].x);
      acc[b].y = fmaf(tv, w.y, acc[b].y);
      acc[b].z = fmaf(tv, w.z, acc[b].z);
      acc[b].w = fmaf(tv, w.w, acc[b].w);
    }
  }
  if(half == 1){
    #pragma unroll
    for(int b=0;b<NB;b++) st4(&red[b][c4], acc[b]);
  }
  __syncthreads();
  if(half == 0){
    #pragma unroll
    for(int b=0;b<NB;b++){
      float4 r = ld4(&red[b][c4]);
      float* dst = t1 + b*FC1DIM + c4;
      atomicAdd(dst+0, acc[b].x + r.x);
      atomicAdd(dst+1, acc[b].y + r.y);
      atomicAdd(dst+2, acc[b].z + r.z);
      atomicAdd(dst+3, acc[b].w + r.w);
    }
  }
}

// ---------- fc1 bias+relu, fc2 + relu, fc3 fused: one block per batch ----------
__global__ __launch_bounds__(128) void k_head2(const float* __restrict__ t1,
                                               const float* __restrict__ fb1,
                                               const float* __restrict__ fw2,
                                               const float* __restrict__ fb2,
                                               const float* __restrict__ fw3,
                                               const float* __restrict__ fb3,
                                               float* __restrict__ pred){
  __shared__ float tr[FC1DIM];
  __shared__ float red[2];
  int b = blockIdx.x, j = threadIdx.x;
  for(int k = j; k < FC1DIM; k += 128)
    tr[k] = fmaxf(t1[b*FC1DIM + k] + fb1[k], 0.f);
  __syncthreads();
  float s = fb2[j];
  for(int k=0;k<FC1DIM;k++) s = fmaf(tr[k], fw2[k*FC2DIM+j], s);
  s = fmaxf(s, 0.f) * fw3[j];
  #pragma unroll
  for(int off=1; off<64; off<<=1) s += __shfl_xor(s, off);
  int lane = j & 63, wv = j >> 6;
  if(lane == 0) red[wv] = s;
  __syncthreads();
  if(j == 0) pred[b] = red[0] + red[1] + fb3[0];
}

extern "C" void kernel_launch(void* const* d_in, const int* in_sizes, int n_in,
                              void* d_out, int out_size, void* d_ws, size_t ws_size,
                              hipStream_t stream) {
  const float* x       = (const float*)d_in[0];
  const float* W1      = (const float*)d_in[1];
  const float* attS1   = (const float*)d_in[2];
  const float* attD1   = (const float*)d_in[3];
  const float* b1      = (const float*)d_in[4];
  const float* W2      = (const float*)d_in[5];
  const float* attS2   = (const float*)d_in[6];
  const float* attD2   = (const float*)d_in[7];
  const float* b2      = (const float*)d_in[8];
  const float* pw1     = (const float*)d_in[9];
  const float* pb1     = (const float*)d_in[10];
  const float* pw2     = (const float*)d_in[11];
  const float* pb2     = (const float*)d_in[12];
  const float* lnw     = (const float*)d_in[13];
  const float* lnb     = (const float*)d_in[14];
  const float* sexemb  = (const float*)d_in[15];
  const float* mutemb  = (const float*)d_in[16];
  const float* agew    = (const float*)d_in[17];
  const float* ageb    = (const float*)d_in[18];
  const float* fw1     = (const float*)d_in[19];
  const float* fb1     = (const float*)d_in[20];
  const float* fw2     = (const float*)d_in[21];
  const float* fb2     = (const float*)d_in[22];
  const float* fw3     = (const float*)d_in[23];
  const float* fb3     = (const float*)d_in[24];
  const float* age     = (const float*)d_in[25];
  const int*   eidx    = (const int*)d_in[26];
  const int*   sex     = (const int*)d_in[27];
  const int*   mut     = (const int*)d_in[28];
  const int E0 = in_sizes[26] / 2;
  const int* esrc = eidx;
  const int* edst = eidx + E0;

  float* out = (float*)d_out;

  // workspace layout (floats first, then bf16/int)
  float* w = (float*)d_ws;
  float* a_s  = w;                        // NTOT*NH
  float* a_d  = a_s + NTOT*NH;
  float* x0r  = a_d + NTOT*NH;            // NTOT (x0r/x1r/x2r contiguous!)
  float* x1r  = x0r + NTOT;
  float* x2r  = x1r + NTOT;
  float* tbuf = x2r + NTOT;               // NB*FCIN
  float* t1   = tbuf + NB*FCIN;           // NB*FC1DIM (atomic fc1 target)
  unsigned short* xb  = (unsigned short*)(t1 + NB*FC1DIM); // NTOT*FIN bf16
  unsigned short* hA  = xb  + (size_t)NTOT*FIN;            // NTOT*HCDIM bf16
  unsigned short* hB  = hA  + (size_t)NTOT*HCDIM;          // NTOT*HCDIM bf16
  unsigned short* W1t = hB  + (size_t)NTOT*HCDIM;          // HCDIM*FIN bf16
  unsigned short* W2t = W1t + HCDIM*FIN;                   // HCDIM*HCDIM bf16
  int* cnt    = (int*)(W2t + HCDIM*HCDIM);   // NTOT
  int* col    = cnt + NTOT;                  // NTOT*CAP
  (void)ws_size; (void)n_in; (void)out_size;

  const int eb = (E0 + 255)/256;

  // prep (mean + bf16 cast + cnt zero), then misc (build | transposes | demo | t1 zero)
  k_prep<<<NTOT/4, 256, 0, stream>>>(x, xb, x0r, cnt);
  k_misc<<<eb + TRB + DEMOB + T1B, 256, 0, stream>>>(esrc, edst, cnt, col, E0, eb,
                                                     W1, W2, W1t, W2t,
                                                     sexemb, mutemb, agew, ageb,
                                                     age, sex, mut, tbuf, t1);

  // GAT layer 1 (attn fused into GEMM epilogue)
  k_gemm_bf<<<dim3(HCDIM/128, NTOT/128), 256, 0, stream>>>(xb, W1t, hA, attS1, attD1, a_s, a_d, NTOT, FIN);
  k_agg<1><<<NTOT/4, 256, 0, stream>>>(hA, a_s, a_d, cnt, col, b1, pw1, pb1, hB, x1r);

  // GAT layer 2
  k_gemm_bf<<<dim3(HCDIM/128, NTOT/128), 256, 0, stream>>>(hB, W2t, hA, attS2, attD2, a_s, a_d, NTOT, HCDIM);
  k_agg<0><<<NTOT/4, 256, 0, stream>>>(hA, a_s, a_d, cnt, col, b2, pw2, pb2, hB, x2r);

  // t = [demo | ln(x0) | ln(x1) | ln(x2)], plus output slots
  k_ln3<<<3*NB, 256, 0, stream>>>(x0r, lnw, lnb, out, tbuf);

  // FC head
  k_fc1p<<<NCH1, 256, 0, stream>>>(tbuf, fw1, t1);
  k_head2<<<NB, 128, 0, stream>>>(t1, fb1, fw2, fb2, fw3, fb3, out);
}

// Round 8
// 272.102 us; speedup vs baseline: 1.1541x; 1.1541x over previous
//
#include <hip/hip_runtime.h>
#include <math.h>

#define NTOT   32000      // total nodes
#define NNODE  2000       // nodes per graph
#define NB     16         // batch (graphs)
#define FIN    128        // input features
#define HCDIM  256        // heads*channels
#define NH     4          // heads
#define FC1DIM 512
#define FC2DIM 128
#define FCIN   12000      // 6*NNODE
#define KC1    50         // fc1 k-rows per block
#define NCH1   240        // 12000/KC1
#define CAP    64         // padded adjacency capacity per node (deg ~ Poisson(12))
#define BK     32
#define LPITCH 40         // LDS row pitch in bf16 (80B: 16B-aligned, bank-spread)
#define TRB    384        // (HCDIM*FIN + HCDIM*HCDIM)/256 transpose blocks
#define DEMOB  375        // NB*3*NNODE/256 demo blocks

typedef __attribute__((ext_vector_type(8))) short bf16x8;
typedef __attribute__((ext_vector_type(4))) float f32x4;

// ---------- small helpers ----------
__device__ inline float4 ld4(const float* p){ return *reinterpret_cast<const float4*>(p); }
__device__ inline void st4(float* p, float4 v){ *reinterpret_cast<float4*>(p) = v; }
__device__ inline float4 add4(float4 a, float4 b){ return make_float4(a.x+b.x,a.y+b.y,a.z+b.z,a.w+b.w); }
__device__ inline float lrelu(float x){ return x > 0.f ? x : 0.2f*x; }
__device__ inline float4 leaky4(float4 a){ return make_float4(lrelu(a.x),lrelu(a.y),lrelu(a.z),lrelu(a.w)); }
__device__ inline float4 exp4u(float4 a){ return make_float4(__expf(a.x),__expf(a.y),__expf(a.z),__expf(a.w)); }
__device__ inline float dot4(float4 a, float4 b){ return a.x*b.x + a.y*b.y + a.z*b.z + a.w*b.w; }
__device__ inline float selh(float4 v, int h){ return h==0 ? v.x : (h==1 ? v.y : (h==2 ? v.z : v.w)); }

__device__ inline unsigned short f2bf(float f){
  unsigned int u = __float_as_uint(f);
  u += 0x7FFFu + ((u >> 16) & 1u);
  return (unsigned short)(u >> 16);
}
__device__ inline float bf2f(unsigned short h){
  return __uint_as_float(((unsigned int)h) << 16);
}
__device__ inline float4 ldbf4(const unsigned short* p){
  ushort4 v = *reinterpret_cast<const ushort4*>(p);
  return make_float4(bf2f(v.x), bf2f(v.y), bf2f(v.z), bf2f(v.w));
}

// ---------- fused: x0 = mean(x,-1), xb = bf16(x), cnt = 0; one wave per row ----------
__global__ __launch_bounds__(256) void k_prep(const float* __restrict__ x,
                                              unsigned short* __restrict__ xb,
                                              float* __restrict__ x0r,
                                              int* __restrict__ cnt){
  int gid = blockIdx.x*256 + threadIdx.x;
  if(gid < NTOT) cnt[gid] = 0;
  int lane = threadIdx.x & 63, wv = threadIdx.x >> 6;
  int n = blockIdx.x*4 + wv;
  const float* r = x + (size_t)n*FIN;
  float2 v = *reinterpret_cast<const float2*>(r + lane*2);
  unsigned int packed = (unsigned int)f2bf(v.x) | ((unsigned int)f2bf(v.y) << 16);
  *reinterpret_cast<unsigned int*>(xb + (size_t)n*FIN + lane*2) = packed;
  float s = v.x + v.y;
  #pragma unroll
  for(int off=1; off<64; off<<=1) s += __shfl_xor(s, off);
  if(lane == 0) x0r[n] = s * (1.0f/FIN);
}

// ---------- misc: adjacency build | W transposes | demo fill ----------
__global__ void k_misc(const int* __restrict__ src, const int* __restrict__ dst,
                       int* __restrict__ cnt, int* __restrict__ col, int e0, int eb,
                       const float* __restrict__ W1, const float* __restrict__ W2,
                       unsigned short* __restrict__ W1t, unsigned short* __restrict__ W2t,
                       const float* __restrict__ sexemb, const float* __restrict__ mutemb,
                       const float* __restrict__ agew, const float* __restrict__ ageb,
                       const float* __restrict__ age, const int* __restrict__ sex,
                       const int* __restrict__ mut, float* __restrict__ t){
  int blk = blockIdx.x;
  if(blk < eb){                                   // ---- adjacency build
    int i = blk*256 + threadIdx.x;
    if(i < e0){
      int d = dst[i];
      int slot = atomicAdd(&cnt[d], 1);
      if(slot < CAP) col[(d<<6) + slot] = src[i];
    }
  } else if(blk < eb + TRB){                      // ---- weight transposes + bf16
    int idx = (blk - eb)*256 + threadIdx.x;
    if(idx < HCDIM*FIN){
      int n = idx / FIN, k = idx - n*FIN;
      W1t[idx] = f2bf(W1[(size_t)k*HCDIM + n]);
    } else {
      int j = idx - HCDIM*FIN;
      int n = j / HCDIM, k = j - n*HCDIM;
      W2t[j] = f2bf(W2[(size_t)k*HCDIM + n]);
    }
  } else {                                        // ---- demographic part of t
    int i = (blk - eb - TRB)*256 + threadIdx.x;
    int b = i / (3*NNODE);
    int j = i - b*(3*NNODE);
    float v;
    if(j < NNODE)          v = sexemb[sex[b]*NNODE + j];
    else if(j < 2*NNODE)   v = mutemb[mut[b]*NNODE + (j - NNODE)];
    else                   v = age[b]*agew[j - 2*NNODE] + ageb[j - 2*NNODE];
    t[b*FCIN + j] = v;
  }
}

// ---------- bf16 MFMA GEMM + fused attention coefficients ----------
// C[M,256] = A[M,K] @ Bt[256,K]^T. 128x128 tile, 4 waves, 64x64 quadrant each.
// Each wave's 64 columns == exactly one head's channels -> compute a_s/a_d from f32 acc.
__global__ __launch_bounds__(256) void k_gemm_bf(const unsigned short* __restrict__ A,
                                                 const unsigned short* __restrict__ Bt,
                                                 unsigned short* __restrict__ C,
                                                 const float* __restrict__ attS,
                                                 const float* __restrict__ attD,
                                                 float* __restrict__ a_s,
                                                 float* __restrict__ a_d,
                                                 int M, int K){
  __shared__ unsigned short As[128][LPITCH];
  __shared__ unsigned short Bs[128][LPITCH];
  int tid = threadIdx.x;
  int lane = tid & 63, wv = tid >> 6;
  int wm = (wv & 1)*64, wn = (wv >> 1)*64;
  int m0 = blockIdx.y*128, n0 = blockIdx.x*128;
  int l15 = lane & 15, lq = lane >> 4;
  f32x4 acc[4][4];
  #pragma unroll
  for(int i=0;i<4;i++)
    #pragma unroll
    for(int j=0;j<4;j++)
      acc[i][j] = (f32x4){0.f,0.f,0.f,0.f};

  int r = tid >> 2, c = (tid & 3)*8;
  for(int k0 = 0; k0 < K; k0 += BK){
    *reinterpret_cast<uint4*>(&As[r][c])    = *reinterpret_cast<const uint4*>(A  + (size_t)(m0+r)*K + k0 + c);
    *reinterpret_cast<uint4*>(&As[r+64][c]) = *reinterpret_cast<const uint4*>(A  + (size_t)(m0+r+64)*K + k0 + c);
    *reinterpret_cast<uint4*>(&Bs[r][c])    = *reinterpret_cast<const uint4*>(Bt + (size_t)(n0+r)*K + k0 + c);
    *reinterpret_cast<uint4*>(&Bs[r+64][c]) = *reinterpret_cast<const uint4*>(Bt + (size_t)(n0+r+64)*K + k0 + c);
    __syncthreads();
    bf16x8 af[4], bfr[4];
    #pragma unroll
    for(int i=0;i<4;i++){
      af[i]  = *reinterpret_cast<const bf16x8*>(&As[wm + i*16 + l15][lq*8]);
      bfr[i] = *reinterpret_cast<const bf16x8*>(&Bs[wn + i*16 + l15][lq*8]);
    }
    #pragma unroll
    for(int mi=0;mi<4;mi++)
      #pragma unroll
      for(int ni=0;ni<4;ni++)
        acc[mi][ni] = __builtin_amdgcn_mfma_f32_16x16x32_bf16(af[mi], bfr[ni], acc[mi][ni], 0, 0, 0);
    __syncthreads();
  }
  // C/D layout: col = lane&15, row = (lane>>4)*4 + reg
  #pragma unroll
  for(int mi=0;mi<4;mi++){
    #pragma unroll
    for(int ni=0;ni<4;ni++){
      int cn = n0 + wn + ni*16 + l15;
      #pragma unroll
      for(int rg=0;rg<4;rg++){
        int rm = m0 + wm + mi*16 + lq*4 + rg;
        C[(size_t)rm*HCDIM + cn] = f2bf(acc[mi][ni][rg]);
      }
    }
  }
  // fused attention coefficients: this wave's 64 cols = head (n0+wn)/64
  int head = (n0 + wn) >> 6;
  float avs[4], avd[4];
  #pragma unroll
  for(int ni=0;ni<4;ni++){
    int cc = ni*16 + l15;
    avs[ni] = attS[head*64 + cc];
    avd[ni] = attD[head*64 + cc];
  }
  #pragma unroll
  for(int mi=0;mi<4;mi++){
    #pragma unroll
    for(int rg=0;rg<4;rg++){
      float ps = 0.f, pd = 0.f;
      #pragma unroll
      for(int ni=0;ni<4;ni++){
        float v = acc[mi][ni][rg];
        ps = fmaf(avs[ni], v, ps);
        pd = fmaf(avd[ni], v, pd);
      }
      #pragma unroll
      for(int off=1; off<16; off<<=1){
        ps += __shfl_xor(ps, off);
        pd += __shfl_xor(pd, off);
      }
      if(l15 == 0){
        int rm = m0 + wm + mi*16 + lq*4 + rg;
        a_s[rm*4 + head] = ps;
        a_d[rm*4 + head] = pd;
      }
    }
  }
}

// ---------- fused softmax + aggregation + bias + relu + pool-dot ----------
// No max-subtraction (|alpha| <~ 1.5 -> exp safe); denominator accumulated per lane
// in the serial loop; col + edge-weights cached in per-wave LDS; no block barrier.
template<int STORE>
__global__ __launch_bounds__(256) void k_agg(const unsigned short* __restrict__ hpre,
                                             const float* __restrict__ a_s,
                                             const float* __restrict__ a_d,
                                             const int* __restrict__ cnt,
                                             const int* __restrict__ col,
                                             const float* __restrict__ bias,
                                             const float* __restrict__ pw,
                                             const float* __restrict__ pb,
                                             unsigned short* __restrict__ hout,
                                             float* __restrict__ xraw){
  __shared__ float4 ew[4][CAP];
  __shared__ int    cols[4][CAP];
  int tid = threadIdx.x;
  int lane = tid & 63, wv = tid >> 6;
  // swizzle: graph g on XCD g%8 so its ~1MB of bf16 hpre rows stays L2-resident
  int blk  = blockIdx.x;
  int xcd  = blk & 7;
  int slot = blk >> 3;
  int half = slot / 500;
  int g    = xcd + 8*half;
  int n    = g*NNODE + (slot - half*500)*4 + wv;
  int f0 = lane*4;
  int hl = lane >> 4;
  float4 ad   = ld4(a_d + n*4);
  float4 asn  = ld4(a_s + n*4);
  float4 eself = exp4u(leaky4(add4(asn, ad)));   // unnormalized self weight
  int deg = min(cnt[n], CAP);
  int base = n << 6;
  if(lane < deg){
    int s = col[base + lane];
    cols[wv][lane] = s;
    ew[wv][lane] = exp4u(leaky4(add4(ld4(a_s + s*4), ad)));
  }
  float es = selh(eself, hl);
  float dsum = es;
  float4 hv = ldbf4(hpre + (size_t)n*HCDIM + f0);
  float4 acc = make_float4(es*hv.x, es*hv.y, es*hv.z, es*hv.w);
  const float* ewf = (const float*)&ew[wv][0];
  const int*   cwf = &cols[wv][0];
  for(int e = 0; e < deg; e++){
    int s = cwf[e];                       // LDS broadcast (wave-uniform)
    float w = ewf[e*4 + hl];
    dsum += w;
    float4 h2 = ldbf4(hpre + (size_t)s*HCDIM + f0);
    acc.x = fmaf(w, h2.x, acc.x); acc.y = fmaf(w, h2.y, acc.y);
    acc.z = fmaf(w, h2.z, acc.z); acc.w = fmaf(w, h2.w, acc.w);
  }
  float invh = 1.0f / (dsum + 1e-16f);
  float4 b4 = ld4(bias + f0);
  acc = make_float4(fmaxf(fmaf(acc.x,invh,b4.x),0.f), fmaxf(fmaf(acc.y,invh,b4.y),0.f),
                    fmaxf(fmaf(acc.z,invh,b4.z),0.f), fmaxf(fmaf(acc.w,invh,b4.w),0.f));
  if(STORE){
    ushort4 hb = make_ushort4(f2bf(acc.x), f2bf(acc.y), f2bf(acc.z), f2bf(acc.w));
    *reinterpret_cast<ushort4*>(hout + (size_t)n*HCDIM + f0) = hb;
  }
  float part = dot4(acc, ld4(pw + f0));
  #pragma unroll
  for(int off=1; off<64; off<<=1) part += __shfl_xor(part, off);
  if(lane == 0) xraw[n] = part + pb[0];
}

// ---------- all three layernorms in one launch: blk = which*16 + b ----------
__global__ __launch_bounds__(256) void k_ln3(const float* __restrict__ xraw0,
                                             const float* __restrict__ lnw,
                                             const float* __restrict__ lnb,
                                             float* __restrict__ out,
                                             float* __restrict__ t){
  int blk = blockIdx.x;
  int b = blk & 15, which = blk >> 4;
  const float* src = xraw0 + which*NTOT + b*NNODE;
  __shared__ float red[8];
  int tid = threadIdx.x, lane = tid & 63, wv = tid >> 6;
  float s = 0.f, ss = 0.f;
  for(int i = tid; i < NNODE; i += 256){ float v = src[i]; s += v; ss += v*v; }
  #pragma unroll
  for(int off=1; off<64; off<<=1){ s += __shfl_xor(s, off); ss += __shfl_xor(ss, off); }
  if(lane == 0){ red[wv] = s; red[4+wv] = ss; }
  __syncthreads();
  s  = red[0]+red[1]+red[2]+red[3];
  ss = red[4]+red[5]+red[6]+red[7];
  float mu  = s * (1.0f/NNODE);
  float var = ss * (1.0f/NNODE) - mu*mu;
  float inv = 1.0f / sqrtf(var + 1e-5f);
  float* o1 = out + 16 + which*(NB*NNODE) + b*NNODE;
  float* o2 = out + 16 + 3*(NB*NNODE) + b*(3*NNODE) + which*NNODE;
  float* o3 = t + b*FCIN + 3*NNODE + which*NNODE;
  for(int i = tid; i < NNODE; i += 256){
    float v = (src[i]-mu)*inv*lnw[i] + lnb[i];
    o1[i] = v; o2[i] = v; o3[i] = v;
  }
}

// ---------- FC1: 240-way split-K, one partial per block (NO atomics) ----------
__global__ __launch_bounds__(256) void k_fc1p(const float* __restrict__ t,
                                              const float* __restrict__ fw1,
                                              float* __restrict__ partial){
  __shared__ float ts[NB][KC1];
  __shared__ float red[NB][FC1DIM];
  int tid = threadIdx.x;
  int half = tid >> 7;
  int c4 = (tid & 127) * 4;
  int k0 = blockIdx.x * KC1;
  for(int i = tid; i < NB*KC1; i += 256){
    int b = i / KC1, kk = i - b*KC1;
    ts[b][kk] = t[b*FCIN + k0 + kk];
  }
  __syncthreads();
  float4 acc[NB];
  #pragma unroll
  for(int b=0;b<NB;b++) acc[b] = make_float4(0.f,0.f,0.f,0.f);
  for(int kk = half; kk < KC1; kk += 2){
    float4 w = ld4(fw1 + (size_t)(k0+kk)*FC1DIM + c4);
    #pragma unroll
    for(int b=0;b<NB;b++){
      float tv = ts[b][kk];
      acc[b].x = fmaf(tv, w.x, acc[b].x);
      acc[b].y = fmaf(tv, w.y, acc[b].y);
      acc[b].z = fmaf(tv, w.z, acc[b].z);
      acc[b].w = fmaf(tv, w.w, acc[b].w);
    }
  }
  if(half == 1){
    #pragma unroll
    for(int b=0;b<NB;b++) st4(&red[b][c4], acc[b]);
  }
  __syncthreads();
  if(half == 0){
    float* po = partial + (size_t)blockIdx.x*(NB*FC1DIM);
    #pragma unroll
    for(int b=0;b<NB;b++){
      float4 r = ld4(&red[b][c4]);
      st4(po + b*FC1DIM + c4, add4(acc[b], r));
    }
  }
}

__global__ void k_fc1r(const float* __restrict__ partial, const float* __restrict__ fb1,
                       float* __restrict__ t1){
  int i = blockIdx.x*blockDim.x + threadIdx.x;
  float s = fb1[i & (FC1DIM-1)];
  for(int c=0;c<NCH1;c++) s += partial[(size_t)c*(NB*FC1DIM) + i];
  t1[i] = fmaxf(s, 0.f);
}

// ---------- fc2 + relu + fc3 fused: one block per batch ----------
__global__ __launch_bounds__(128) void k_head2(const float* __restrict__ t1,
                                               const float* __restrict__ fw2,
                                               const float* __restrict__ fb2,
                                               const float* __restrict__ fw3,
                                               const float* __restrict__ fb3,
                                               float* __restrict__ pred){
  __shared__ float red[2];
  int b = blockIdx.x, j = threadIdx.x;
  const float* tr = t1 + b*FC1DIM;
  float s = fb2[j];
  for(int k=0;k<FC1DIM;k++) s = fmaf(tr[k], fw2[k*FC2DIM+j], s);
  s = fmaxf(s, 0.f) * fw3[j];
  #pragma unroll
  for(int off=1; off<64; off<<=1) s += __shfl_xor(s, off);
  int lane = j & 63, wv = j >> 6;
  if(lane == 0) red[wv] = s;
  __syncthreads();
  if(j == 0) pred[b] = red[0] + red[1] + fb3[0];
}

extern "C" void kernel_launch(void* const* d_in, const int* in_sizes, int n_in,
                              void* d_out, int out_size, void* d_ws, size_t ws_size,
                              hipStream_t stream) {
  const float* x       = (const float*)d_in[0];
  const float* W1      = (const float*)d_in[1];
  const float* attS1   = (const float*)d_in[2];
  const float* attD1   = (const float*)d_in[3];
  const float* b1      = (const float*)d_in[4];
  const float* W2      = (const float*)d_in[5];
  const float* attS2   = (const float*)d_in[6];
  const float* attD2   = (const float*)d_in[7];
  const float* b2      = (const float*)d_in[8];
  const float* pw1     = (const float*)d_in[9];
  const float* pb1     = (const float*)d_in[10];
  const float* pw2     = (const float*)d_in[11];
  const float* pb2     = (const float*)d_in[12];
  const float* lnw     = (const float*)d_in[13];
  const float* lnb     = (const float*)d_in[14];
  const float* sexemb  = (const float*)d_in[15];
  const float* mutemb  = (const float*)d_in[16];
  const float* agew    = (const float*)d_in[17];
  const float* ageb    = (const float*)d_in[18];
  const float* fw1     = (const float*)d_in[19];
  const float* fb1     = (const float*)d_in[20];
  const float* fw2     = (const float*)d_in[21];
  const float* fb2     = (const float*)d_in[22];
  const float* fw3     = (const float*)d_in[23];
  const float* fb3     = (const float*)d_in[24];
  const float* age     = (const float*)d_in[25];
  const int*   eidx    = (const int*)d_in[26];
  const int*   sex     = (const int*)d_in[27];
  const int*   mut     = (const int*)d_in[28];
  const int E0 = in_sizes[26] / 2;
  const int* esrc = eidx;
  const int* edst = eidx + E0;

  float* out = (float*)d_out;

  // workspace layout (floats first, then bf16/int)
  float* w = (float*)d_ws;
  float* a_s  = w;                        // NTOT*NH
  float* a_d  = a_s + NTOT*NH;
  float* x0r  = a_d + NTOT*NH;            // NTOT (x0r/x1r/x2r contiguous!)
  float* x1r  = x0r + NTOT;
  float* x2r  = x1r + NTOT;
  float* tbuf = x2r + NTOT;               // NB*FCIN
  float* part = tbuf + NB*FCIN;           // NCH1*NB*FC1DIM
  float* t1   = part + (size_t)NCH1*NB*FC1DIM; // NB*FC1DIM
  unsigned short* xb  = (unsigned short*)(t1 + NB*FC1DIM); // NTOT*FIN bf16
  unsigned short* hA  = xb  + (size_t)NTOT*FIN;            // NTOT*HCDIM bf16
  unsigned short* hB  = hA  + (size_t)NTOT*HCDIM;          // NTOT*HCDIM bf16
  unsigned short* W1t = hB  + (size_t)NTOT*HCDIM;          // HCDIM*FIN bf16
  unsigned short* W2t = W1t + HCDIM*FIN;                   // HCDIM*HCDIM bf16
  int* cnt    = (int*)(W2t + HCDIM*HCDIM);   // NTOT
  int* col    = cnt + NTOT;                  // NTOT*CAP
  (void)ws_size; (void)n_in; (void)out_size;

  const int eb = (E0 + 255)/256;

  // prep (mean + bf16 cast + cnt zero), then misc (build | transposes | demo)
  k_prep<<<NTOT/4, 256, 0, stream>>>(x, xb, x0r, cnt);
  k_misc<<<eb + TRB + DEMOB, 256, 0, stream>>>(esrc, edst, cnt, col, E0, eb,
                                               W1, W2, W1t, W2t,
                                               sexemb, mutemb, agew, ageb,
                                               age, sex, mut, tbuf);

  // GAT layer 1 (attn fused into GEMM epilogue)
  k_gemm_bf<<<dim3(HCDIM/128, NTOT/128), 256, 0, stream>>>(xb, W1t, hA, attS1, attD1, a_s, a_d, NTOT, FIN);
  k_agg<1><<<NTOT/4, 256, 0, stream>>>(hA, a_s, a_d, cnt, col, b1, pw1, pb1, hB, x1r);

  // GAT layer 2
  k_gemm_bf<<<dim3(HCDIM/128, NTOT/128), 256, 0, stream>>>(hB, W2t, hA, attS2, attD2, a_s, a_d, NTOT, HCDIM);
  k_agg<0><<<NTOT/4, 256, 0, stream>>>(hA, a_s, a_d, cnt, col, b2, pw2, pb2, hB, x2r);

  // t = [demo | ln(x0) | ln(x1) | ln(x2)], plus output slots
  k_ln3<<<3*NB, 256, 0, stream>>>(x0r, lnw, lnb, out, tbuf);

  // FC head
  k_fc1p<<<NCH1, 256, 0, stream>>>(tbuf, fw1, part);
  k_fc1r<<<(NB*FC1DIM)/256, 256, 0, stream>>>(part, fb1, t1);
  k_head2<<<NB, 128, 0, stream>>>(t1, fw2, fb2, fw3, fb3, out);
}